// Round 7
// baseline (208.321 us; speedup 1.0000x reference)
//
#include <hip/hip_runtime.h>

// Problem constants (from reference setup_inputs)
constexpr int B  = 32;
constexpr int C  = 3;
constexpr int H  = 512;
constexpr int W  = 512;
constexpr int HP = H / 4;    // 128 pooled rows
constexpr int WP = W / 4;    // 128 pooled cols
constexpr int NP = B * HP * WP;   // 524288 pooled pixels
constexpr int W4 = W / 4;    // 128 float4 per image row

// v8: dual-path wave-split.
// v6 (all-nt) = ~54us kernel (~3.96 TB/s); v7 (2x waves/CU) neutral ->
// nt-regime BW is occupancy-invariant; suspect per-CU outstanding-miss
// slots (~44 x 128B @ ~900cy = 15 GB/s/CU x 256 = 3.85 TB/s ~= measured).
// The cached L2/L3 path served ~1.4 TB/s CONCURRENTLY in v1-v5 but was
// coupled inside each wave's in-order vmcnt queue (hits stuck behind
// misses). v8 partitions BY WAVE: waves 0-7 read x with CACHED loads
// (x=100.7MB, partially L3-resident from restore-fills + read-alloc),
// waves 8-15 read pred with NT loads (pure HBM channel). Homogeneous
// per-wave queues -> decoupled stalls; the two service channels add.
// Decision rule: >= v6's bench -> revert to v6, declare nt-read roofline.
typedef float f4 __attribute__((ext_vector_type(4)));

constexpr int ROWS_PB     = 16;              // owned pooled rows per block
constexpr int HROWS       = ROWS_PB + 1;     // 17 incl. top halo
constexpr int BLK_PER_IMG = HP / ROWS_PB;    // 8
constexpr int NBLOCKS     = B * BLK_PER_IMG; // 256 -> 1 block/CU
constexpr int NTHR        = 1024;
constexpr int HALF        = NTHR / 2;        // 512 threads per array-path
constexpr int NTASK       = C * HROWS * WP;  // 6528 (c,row,q) tasks per array

__global__ __launch_bounds__(1024, 1) void spatial_loss_fused(
        const float* __restrict__ x,
        const float* __restrict__ pred,
        float* __restrict__ out) {
    __shared__ float sm_x[C * HROWS][WP];  // 51 x 128 = 26.1 KB x-sums
    __shared__ float sm_p[C * HROWS][WP];  // 51 x 128 = 26.1 KB pred-sums
    __shared__ float P[HROWS][WP];         // 17 x 128 pooled diff tile
    __shared__ float ws_red[16];

    // Bijective XCD swizzle (256 % 8 == 0): vertically-adjacent blocks
    // (which share a halo row) land on the same XCD's L2.
    int orig = blockIdx.x;
    int blk  = (orig & 7) * (NBLOCKS / 8) + (orig >> 3);
    int b    = blk >> 3;          // image
    int br   = blk & 7;           // block-row within image
    int py0  = br * ROWS_PB;
    int tid  = threadIdx.x;
    int half = tid >> 9;          // 0 = x-path (cached), 1 = pred-path (nt)
    int lid  = tid & (HALF - 1);  // 0..511 within the half

    const f4* __restrict__ xb = (const f4*)x;
    const f4* __restrict__ pb = (const f4*)pred;

    // ---- Phase A: per-(channel, pooled-pixel) partial sums, one array
    // per wave-group. task t -> q = t&127 (float4 col), cr = t>>7 in
    // 0..50 -> rr = cr/3 (local pooled row incl. top halo), c = cr%3.
    // Wave lanes have consecutive q -> every load is 1KB contiguous.
    // 6528 / 512 = 12.75 iters; the partial tail is 384 thr = 6 waves
    // (wave-uniform).
    if (half == 0) {
        // x path: REGULAR cached loads (L2/L3 channel).
        for (int t = lid; t < NTASK; t += HALF) {
            int q  = t & 127;
            int cr = t >> 7;
            int rr = cr / 3;
            int c  = cr - 3 * rr;
            int gy = py0 + rr - 1;
            float s = 0.0f;
            if (gy >= 0) {
                int a = ((b * C + c) * H + gy * 4) * W4 + q;
                f4 v0 = xb[a];
                f4 v1 = xb[a + W4];
                f4 v2 = xb[a + 2 * W4];
                f4 v3 = xb[a + 3 * W4];
                float s0 = (v0.x + v0.y) + (v0.z + v0.w);
                float s1 = (v1.x + v1.y) + (v1.z + v1.w);
                float s2 = (v2.x + v2.y) + (v2.z + v2.w);
                float s3 = (v3.x + v3.y) + (v3.z + v3.w);
                s = (s0 + s1) + (s2 + s3);
            }
            sm_x[cr][q] = s;
        }
    } else {
        // pred path: NON-TEMPORAL loads (pure HBM channel, no allocation).
        for (int t = lid; t < NTASK; t += HALF) {
            int q  = t & 127;
            int cr = t >> 7;
            int rr = cr / 3;
            int c  = cr - 3 * rr;
            int gy = py0 + rr - 1;
            float s = 0.0f;
            if (gy >= 0) {
                int a = ((b * C + c) * H + gy * 4) * W4 + q;
                f4 v0 = __builtin_nontemporal_load(pb + a);
                f4 v1 = __builtin_nontemporal_load(pb + a + W4);
                f4 v2 = __builtin_nontemporal_load(pb + a + 2 * W4);
                f4 v3 = __builtin_nontemporal_load(pb + a + 3 * W4);
                float s0 = (v0.x + v0.y) + (v0.z + v0.w);
                float s1 = (v1.x + v1.y) + (v1.z + v1.w);
                float s2 = (v2.x + v2.y) + (v2.z + v2.w);
                float s3 = (v3.x + v3.y) + (v3.z + v3.w);
                s = (s0 + s1) + (s2 + s3);
            }
            sm_p[cr][q] = s;
        }
    }
    __syncthreads();

    // ---- Phase B1: channel-sum diff -> pooled tile P (17 x 128) ----
    // For br==0 the halo tasks wrote 0 to both sm arrays -> P[0]=0.
    for (int i = tid; i < HROWS * WP; i += NTHR) {
        int q  = i & 127;
        int pr = i >> 7;              // 0..16
        float sx = sm_x[3 * pr][q] + sm_x[3 * pr + 1][q] + sm_x[3 * pr + 2][q];
        float sp = sm_p[3 * pr][q] + sm_p[3 * pr + 1][q] + sm_p[3 * pr + 2][q];
        P[pr][q] = (sx - sp) * (1.0f / 48.0f);
    }
    __syncthreads();

    // ---- Phase B2: pair-counted gradient sum over owned 16x128 pixels ----
    // E*NP = 2*sum(adjacent-pair diffs^2) + sum(border p^2); this block
    // counts the up-pair and left-pair of its OWNED pixels. Zero halo at
    // the image top makes the border term c^2 with weight 1 automatically.
    float acc = 0.0f;
    #pragma unroll
    for (int j = 0; j < (ROWS_PB * WP) / NTHR; ++j) {   // 2
        int i  = tid + j * NTHR;
        int q  = i & 127;
        int r  = i >> 7;              // 0..15
        int gy = py0 + r;
        float cv = P[r + 1][q];
        float up = P[r][q];                       // 0 if gy==0
        float lf = (q > 0) ? P[r + 1][q - 1] : 0.0f;
        float dy = cv - up;
        float dx = cv - lf;
        float wy = (gy > 0) ? 2.0f : 1.0f;        // interior pair counted twice
        float wx = (q  > 0) ? 2.0f : 1.0f;
        acc += wy * dy * dy + wx * dx * dx;
        if (gy == HP - 1) acc += cv * cv;         // bottom border (d_down)
        if (q  == WP - 1) acc += cv * cv;         // right border (d_right)
    }

    // wave64 shuffle reduce -> LDS -> one pre-scaled atomicAdd per block
    #pragma unroll
    for (int off = 32; off > 0; off >>= 1)
        acc += __shfl_down(acc, off, 64);

    int lane = tid & 63;
    int wid  = tid >> 6;              // 0..15
    if (lane == 0) ws_red[wid] = acc;
    __syncthreads();
    if (tid == 0) {
        float s = 0.0f;
        #pragma unroll
        for (int k = 0; k < 16; ++k) s += ws_red[k];
        atomicAdd(out, s * (1.0f / (float)NP));
    }
}

extern "C" void kernel_launch(void* const* d_in, const int* in_sizes, int n_in,
                              void* d_out, int out_size, void* d_ws, size_t ws_size,
                              hipStream_t stream) {
    const float* x    = (const float*)d_in[0];
    const float* pred = (const float*)d_in[1];
    float* out = (float*)d_out;

    // d_out is poisoned 0xAA before every launch — zero it (capture-safe).
    hipMemsetAsync(out, 0, sizeof(float), stream);

    spatial_loss_fused<<<NBLOCKS, NTHR, 0, stream>>>(x, pred, out);
}

// Round 8
// 205.587 us; speedup vs baseline: 1.0133x; 1.0133x over previous
//
#include <hip/hip_runtime.h>

// Problem constants (from reference setup_inputs)
constexpr int B  = 32;
constexpr int C  = 3;
constexpr int H  = 512;
constexpr int W  = 512;
constexpr int HP = H / 4;    // 128 pooled rows
constexpr int WP = W / 4;    // 128 pooled cols
constexpr int NP = B * HP * WP;   // 524288 pooled pixels
constexpr int W4 = W / 4;    // 128 float4 per image row

// v9: ASYMMETRIC dual-channel split.
// v8 measured the two memory channels cleanly:
//   - cached channel (L3-hit service): 1.77 TB/s (x was ~fully L3-resident:
//     FETCH_SIZE == pred bytes only)
//   - nt channel (HBM read): 3.96 TB/s (v6/v7), wave-count-invariant
// v8's 50/50 byte split made the cached channel the critical path (60.5us)
// while nt idled after ~27us. Optimal split: cached gets
// f = 1.77/(1.77+3.96) ~= 31% of all bytes -> both channels finish at
// ~214MB / 5.73 TB/s ~= 37us.
// Since x is L3-resident and pred is not: cached waves (0-7) read the
// FIRST 61% of x-tasks (65.6MB, L3 hits); nt waves (8-15) read ALL of
// pred + the remaining 39% of x. NCX = 3968 of 6528 tasks.
typedef float f4 __attribute__((ext_vector_type(4)));

constexpr int ROWS_PB     = 16;              // owned pooled rows per block
constexpr int HROWS       = ROWS_PB + 1;     // 17 incl. top halo
constexpr int BLK_PER_IMG = HP / ROWS_PB;    // 8
constexpr int NBLOCKS     = B * BLK_PER_IMG; // 256 -> 1 block/CU
constexpr int NTHR        = 1024;
constexpr int HALF        = NTHR / 2;        // 512 threads per channel
constexpr int NTASK       = C * HROWS * WP;  // 6528 (c,row,q) tasks per array
constexpr int NCX         = 3968;            // x-tasks on the cached channel (~61%)

__global__ __launch_bounds__(1024, 1) void spatial_loss_fused(
        const float* __restrict__ x,
        const float* __restrict__ pred,
        float* __restrict__ out) {
    __shared__ float sm_x[C * HROWS][WP];  // 51 x 128 = 26.1 KB x-sums
    __shared__ float sm_p[C * HROWS][WP];  // 51 x 128 = 26.1 KB pred-sums
    __shared__ float P[HROWS][WP];         // 17 x 128 pooled diff tile
    __shared__ float ws_red[16];

    // Bijective XCD swizzle (256 % 8 == 0): vertically-adjacent blocks
    // (which share a halo row) land on the same XCD's L2.
    int orig = blockIdx.x;
    int blk  = (orig & 7) * (NBLOCKS / 8) + (orig >> 3);
    int b    = blk >> 3;          // image
    int br   = blk & 7;           // block-row within image
    int py0  = br * ROWS_PB;
    int tid  = threadIdx.x;
    int half = tid >> 9;          // 0 = cached channel, 1 = nt channel
    int lid  = tid & (HALF - 1);  // 0..511 within the channel

    const f4* __restrict__ xb = (const f4*)x;
    const f4* __restrict__ pb = (const f4*)pred;

    // ---- Phase A: per-(channel-task) partial sums ----
    // task t -> q = t&127 (float4 col), cr = t>>7 in 0..50 ->
    //   rr = cr/3 (local pooled row incl. top halo), c = cr%3.
    // Wave lanes have consecutive q -> every load is 1KB contiguous.
    // Time balance: cached 3968 tasks / 1.77 ~= nt (6528+2560) / 3.96.
    if (half == 0) {
        // Cached channel: x-tasks [0, NCX) with regular loads (L3 hits).
        for (int t = lid; t < NCX; t += HALF) {
            int q  = t & 127;
            int cr = t >> 7;
            int rr = cr / 3;
            int c  = cr - 3 * rr;
            int gy = py0 + rr - 1;
            float s = 0.0f;
            if (gy >= 0) {
                int a = ((b * C + c) * H + gy * 4) * W4 + q;
                f4 v0 = xb[a];
                f4 v1 = xb[a + W4];
                f4 v2 = xb[a + 2 * W4];
                f4 v3 = xb[a + 3 * W4];
                float s0 = (v0.x + v0.y) + (v0.z + v0.w);
                float s1 = (v1.x + v1.y) + (v1.z + v1.w);
                float s2 = (v2.x + v2.y) + (v2.z + v2.w);
                float s3 = (v3.x + v3.y) + (v3.z + v3.w);
                s = (s0 + s1) + (s2 + s3);
            }
            sm_x[cr][q] = s;
        }
    } else {
        // NT channel: all pred-tasks, then the x-task remainder [NCX, NTASK).
        for (int t = lid; t < NTASK; t += HALF) {
            int q  = t & 127;
            int cr = t >> 7;
            int rr = cr / 3;
            int c  = cr - 3 * rr;
            int gy = py0 + rr - 1;
            float s = 0.0f;
            if (gy >= 0) {
                int a = ((b * C + c) * H + gy * 4) * W4 + q;
                f4 v0 = __builtin_nontemporal_load(pb + a);
                f4 v1 = __builtin_nontemporal_load(pb + a + W4);
                f4 v2 = __builtin_nontemporal_load(pb + a + 2 * W4);
                f4 v3 = __builtin_nontemporal_load(pb + a + 3 * W4);
                float s0 = (v0.x + v0.y) + (v0.z + v0.w);
                float s1 = (v1.x + v1.y) + (v1.z + v1.w);
                float s2 = (v2.x + v2.y) + (v2.z + v2.w);
                float s3 = (v3.x + v3.y) + (v3.z + v3.w);
                s = (s0 + s1) + (s2 + s3);
            }
            sm_p[cr][q] = s;
        }
        for (int t = NCX + lid; t < NTASK; t += HALF) {
            int q  = t & 127;
            int cr = t >> 7;
            int rr = cr / 3;
            int c  = cr - 3 * rr;
            int gy = py0 + rr - 1;   // always >= 0 here (NCX > halo tasks)
            float s = 0.0f;
            if (gy >= 0) {
                int a = ((b * C + c) * H + gy * 4) * W4 + q;
                f4 v0 = __builtin_nontemporal_load(xb + a);
                f4 v1 = __builtin_nontemporal_load(xb + a + W4);
                f4 v2 = __builtin_nontemporal_load(xb + a + 2 * W4);
                f4 v3 = __builtin_nontemporal_load(xb + a + 3 * W4);
                float s0 = (v0.x + v0.y) + (v0.z + v0.w);
                float s1 = (v1.x + v1.y) + (v1.z + v1.w);
                float s2 = (v2.x + v2.y) + (v2.z + v2.w);
                float s3 = (v3.x + v3.y) + (v3.z + v3.w);
                s = (s0 + s1) + (s2 + s3);
            }
            sm_x[cr][q] = s;
        }
    }
    __syncthreads();

    // ---- Phase B1: channel-sum diff -> pooled tile P (17 x 128) ----
    // For br==0 the halo tasks wrote 0 to both sm arrays -> P[0]=0.
    for (int i = tid; i < HROWS * WP; i += NTHR) {
        int q  = i & 127;
        int pr = i >> 7;              // 0..16
        float sx = sm_x[3 * pr][q] + sm_x[3 * pr + 1][q] + sm_x[3 * pr + 2][q];
        float sp = sm_p[3 * pr][q] + sm_p[3 * pr + 1][q] + sm_p[3 * pr + 2][q];
        P[pr][q] = (sx - sp) * (1.0f / 48.0f);
    }
    __syncthreads();

    // ---- Phase B2: pair-counted gradient sum over owned 16x128 pixels ----
    // E*NP = 2*sum(adjacent-pair diffs^2) + sum(border p^2); this block
    // counts the up-pair and left-pair of its OWNED pixels. Zero halo at
    // the image top makes the border term c^2 with weight 1 automatically.
    float acc = 0.0f;
    #pragma unroll
    for (int j = 0; j < (ROWS_PB * WP) / NTHR; ++j) {   // 2
        int i  = tid + j * NTHR;
        int q  = i & 127;
        int r  = i >> 7;              // 0..15
        int gy = py0 + r;
        float cv = P[r + 1][q];
        float up = P[r][q];                       // 0 if gy==0
        float lf = (q > 0) ? P[r + 1][q - 1] : 0.0f;
        float dy = cv - up;
        float dx = cv - lf;
        float wy = (gy > 0) ? 2.0f : 1.0f;        // interior pair counted twice
        float wx = (q  > 0) ? 2.0f : 1.0f;
        acc += wy * dy * dy + wx * dx * dx;
        if (gy == HP - 1) acc += cv * cv;         // bottom border (d_down)
        if (q  == WP - 1) acc += cv * cv;         // right border (d_right)
    }

    // wave64 shuffle reduce -> LDS -> one pre-scaled atomicAdd per block
    #pragma unroll
    for (int off = 32; off > 0; off >>= 1)
        acc += __shfl_down(acc, off, 64);

    int lane = tid & 63;
    int wid  = tid >> 6;              // 0..15
    if (lane == 0) ws_red[wid] = acc;
    __syncthreads();
    if (tid == 0) {
        float s = 0.0f;
        #pragma unroll
        for (int k = 0; k < 16; ++k) s += ws_red[k];
        atomicAdd(out, s * (1.0f / (float)NP));
    }
}

extern "C" void kernel_launch(void* const* d_in, const int* in_sizes, int n_in,
                              void* d_out, int out_size, void* d_ws, size_t ws_size,
                              hipStream_t stream) {
    const float* x    = (const float*)d_in[0];
    const float* pred = (const float*)d_in[1];
    float* out = (float*)d_out;

    // d_out is poisoned 0xAA before every launch — zero it (capture-safe).
    hipMemsetAsync(out, 0, sizeof(float), stream);

    spatial_loss_fused<<<NBLOCKS, NTHR, 0, stream>>>(x, pred, out);
}

// Round 9
// 193.277 us; speedup vs baseline: 1.0778x; 1.0637x over previous
//
#include <hip/hip_runtime.h>

// Problem constants (from reference setup_inputs)
constexpr int B  = 32;
constexpr int C  = 3;
constexpr int H  = 512;
constexpr int W  = 512;
constexpr int HP = H / 4;    // 128 pooled rows
constexpr int WP = W / 4;    // 128 pooled cols
constexpr int NP = B * HP * WP;   // 524288 pooled pixels
constexpr int W4 = W / 4;    // 128 float4 per image row

// v10 == v6 revert (proven best: bench 195.6us, kernel ~54us ~= 3.96 TB/s).
// Session findings baked in:
//  - Cached-load streaming pins at ~2.8 TB/s: the Infinity-Cache-HIT
//    service path (~1.8 TB/s) rate-limits a coupled hit/miss stream
//    (v1-v5: invariant to occupancy 10->66%, granule 512B->1KB, ILP).
//  - Non-temporal loads bypass L3 allocation -> whole stream rides the
//    HBM read path: 3.96-4.0 TB/s (v6), occupancy-invariant (v7).
//  - Dual-channel wave-splits (cached x || nt pred) do NOT add: 50/50
//    split 3.54 TB/s (v8), balanced 31/69 split ~3.6 TB/s (v9) -> one
//    shared inbound read path capped ~4.0 TB/s; all-nt is optimal.
//  - Write path is separate and faster (harness fill: 6.8 TB/s).
// Floor: 201.3 MB logical / 3.96 TB/s = 50.8us; this kernel reads
// 214 MB (6.25% one-sided halo) -> ~54us, within ~6%. Halo elimination
// via 2nd kernel or coop grid-sync costs ~= its 3.2us saving. Roofline.
typedef float f4 __attribute__((ext_vector_type(4)));

constexpr int ROWS_PB     = 16;              // owned pooled rows per block
constexpr int HROWS       = ROWS_PB + 1;     // 17 incl. top halo
constexpr int BLK_PER_IMG = HP / ROWS_PB;    // 8
constexpr int NBLOCKS     = B * BLK_PER_IMG; // 256 -> 1 block/CU
constexpr int NTHR        = 1024;
constexpr int NTASK       = C * HROWS * WP;  // 6528 load-tasks per block

__global__ __launch_bounds__(1024, 1) void spatial_loss_fused(
        const float* __restrict__ x,
        const float* __restrict__ pred,
        float* __restrict__ out) {
    __shared__ float sm[C * HROWS][WP];   // 51 x 128 = 26.1 KB per-(c,row) partials
    __shared__ float P[HROWS][WP];        // 17 x 128 pooled diff tile
    __shared__ float ws_red[16];

    // Bijective XCD swizzle (256 % 8 == 0): vertically-adjacent blocks
    // (which share a halo row) land on the same XCD's L2.
    int orig = blockIdx.x;
    int blk  = (orig & 7) * (NBLOCKS / 8) + (orig >> 3);
    int b    = blk >> 3;          // image
    int br   = blk & 7;           // block-row within image
    int py0  = br * ROWS_PB;
    int tid  = threadIdx.x;

    const f4* __restrict__ xb = (const f4*)x;
    const f4* __restrict__ pb = (const f4*)pred;

    // ---- Phase A: per-(channel, pooled-pixel) partial diffs ----
    // task t -> q = t&127 (float4 col), cr = t>>7 in 0..50 ->
    //   rr = cr/3 (local pooled row incl. top halo), c = cr%3.
    // Wave lanes have consecutive q -> every load is 1KB contiguous.
    // 6528 tasks / 1024 thr = 7 iters (last = 384 thr, wave-uniform).
    for (int t = tid; t < NTASK; t += NTHR) {
        int q  = t & 127;
        int cr = t >> 7;
        int rr = cr / 3;              // 0..16 (0 = top halo row)
        int c  = cr - 3 * rr;
        int gy = py0 + rr - 1;        // pooled row, -1..127
        float s = 0.0f;
        if (gy >= 0) {                // wave-uniform guard (br==0 only)
            int a = ((b * C + c) * H + gy * 4) * W4 + q;
            // 8 independent non-temporal loads batched before arithmetic.
            f4 x0 = __builtin_nontemporal_load(xb + a);
            f4 x1 = __builtin_nontemporal_load(xb + a + W4);
            f4 x2 = __builtin_nontemporal_load(xb + a + 2 * W4);
            f4 x3 = __builtin_nontemporal_load(xb + a + 3 * W4);
            f4 p0 = __builtin_nontemporal_load(pb + a);
            f4 p1 = __builtin_nontemporal_load(pb + a + W4);
            f4 p2 = __builtin_nontemporal_load(pb + a + 2 * W4);
            f4 p3 = __builtin_nontemporal_load(pb + a + 3 * W4);
            float s0 = (x0.x - p0.x) + (x0.y - p0.y) + (x0.z - p0.z) + (x0.w - p0.w);
            float s1 = (x1.x - p1.x) + (x1.y - p1.y) + (x1.z - p1.z) + (x1.w - p1.w);
            float s2 = (x2.x - p2.x) + (x2.y - p2.y) + (x2.z - p2.z) + (x2.w - p2.w);
            float s3 = (x3.x - p3.x) + (x3.y - p3.y) + (x3.z - p3.z) + (x3.w - p3.w);
            s = (s0 + s1) + (s2 + s3);
        }
        sm[cr][q] = s;   // lanes -> consecutive q, conflict-free
    }
    __syncthreads();

    // ---- Phase B1: channel-sum -> pooled diff tile P (17 x 128) ----
    // For br==0 the halo tasks wrote s=0 -> P[0]=0 at the image top.
    for (int i = tid; i < HROWS * WP; i += NTHR) {
        int q  = i & 127;
        int pr = i >> 7;              // 0..16
        P[pr][q] = (sm[3 * pr][q] + sm[3 * pr + 1][q] + sm[3 * pr + 2][q])
                   * (1.0f / 48.0f);
    }
    __syncthreads();

    // ---- Phase B2: pair-counted gradient sum over owned 16x128 pixels ----
    // E*NP = 2*sum(adjacent-pair diffs^2) + sum(border p^2); this block
    // counts the up-pair and left-pair of its OWNED pixels. Zero halo at
    // the image top makes the border term c^2 with weight 1 automatically.
    float acc = 0.0f;
    #pragma unroll
    for (int j = 0; j < (ROWS_PB * WP) / NTHR; ++j) {   // 2
        int i  = tid + j * NTHR;
        int q  = i & 127;
        int r  = i >> 7;              // 0..15
        int gy = py0 + r;
        float cv = P[r + 1][q];
        float up = P[r][q];                       // 0 if gy==0
        float lf = (q > 0) ? P[r + 1][q - 1] : 0.0f;
        float dy = cv - up;
        float dx = cv - lf;
        float wy = (gy > 0) ? 2.0f : 1.0f;        // interior pair counted twice
        float wx = (q  > 0) ? 2.0f : 1.0f;
        acc += wy * dy * dy + wx * dx * dx;
        if (gy == HP - 1) acc += cv * cv;         // bottom border (d_down)
        if (q  == WP - 1) acc += cv * cv;         // right border (d_right)
    }

    // wave64 shuffle reduce -> LDS -> one pre-scaled atomicAdd per block
    #pragma unroll
    for (int off = 32; off > 0; off >>= 1)
        acc += __shfl_down(acc, off, 64);

    int lane = tid & 63;
    int wid  = tid >> 6;              // 0..15
    if (lane == 0) ws_red[wid] = acc;
    __syncthreads();
    if (tid == 0) {
        float s = 0.0f;
        #pragma unroll
        for (int k = 0; k < 16; ++k) s += ws_red[k];
        atomicAdd(out, s * (1.0f / (float)NP));
    }
}

extern "C" void kernel_launch(void* const* d_in, const int* in_sizes, int n_in,
                              void* d_out, int out_size, void* d_ws, size_t ws_size,
                              hipStream_t stream) {
    const float* x    = (const float*)d_in[0];
    const float* pred = (const float*)d_in[1];
    float* out = (float*)d_out;

    // d_out is poisoned 0xAA before every launch — zero it (capture-safe).
    hipMemsetAsync(out, 0, sizeof(float), stream);

    spatial_loss_fused<<<NBLOCKS, NTHR, 0, stream>>>(x, pred, out);
}